// Round 9
// baseline (128.590 us; speedup 1.0000x reference)
//
#include <hip/hip_runtime.h>
#include <cstdint>

#define B_ 4
#define C_ 128
#define INNER_ 64
#define N_ 4096
#define SPLITS 12                 // key-dimension splits (uneven, tile-granular)
#define KT 32                     // key-tile size
#define TT 128                    // total key tiles = N_/KT

typedef __attribute__((ext_vector_type(8))) short short8;
typedef __attribute__((ext_vector_type(4))) short bf16x4;
typedef __attribute__((ext_vector_type(4))) float f32x4;
typedef __attribute__((ext_vector_type(2))) unsigned u32x2;

typedef const __attribute__((address_space(1))) void* gp_t;
typedef __attribute__((address_space(3))) void* lp_t;

__device__ __forceinline__ short f2bf(float f) {
  unsigned u = __builtin_bit_cast(unsigned, f);
  unsigned r = (u + 0x7FFFu + ((u >> 16) & 1u)) >> 16;
  return (short)r;
}
__device__ __forceinline__ float bf2f(short s) {
  return __builtin_bit_cast(float, ((unsigned)(unsigned short)s) << 16);
}
__device__ __forceinline__ float fexp2(float x) {
#if __has_builtin(__builtin_amdgcn_exp2f)
  return __builtin_amdgcn_exp2f(x);
#else
  return exp2f(x);
#endif
}
__device__ __forceinline__ unsigned pk2(float lo, float hi) {
#if __has_builtin(__builtin_amdgcn_cvt_pk_bf16_f32)
  typedef __attribute__((ext_vector_type(2))) __bf16 bfp;
  bfp v = __builtin_amdgcn_cvt_pk_bf16_f32(lo, hi);
  return __builtin_bit_cast(unsigned, v);
#else
  return (unsigned)(unsigned short)f2bf(lo) | ((unsigned)(unsigned short)f2bf(hi) << 16);
#endif
}

// K=16 MFMA: D = A(16x16)*B(16x16)+C. A/B frags: 4 bf16/lane, k = quad*4+j.
__device__ __forceinline__ f32x4 mfma16(bf16x4 a, bf16x4 b, f32x4 c) {
#if __has_builtin(__builtin_amdgcn_mfma_f32_16x16x16bf16_1k)
  return __builtin_amdgcn_mfma_f32_16x16x16bf16_1k(a, b, c, 0, 0, 0);
#elif __has_builtin(__builtin_amdgcn_mfma_f32_16x16x16_bf16)
  return __builtin_amdgcn_mfma_f32_16x16x16_bf16(a, b, c, 0, 0, 0);
#else
  f32x4 d;
  asm volatile("v_mfma_f32_16x16x16_bf16 %0, %1, %2, %3"
               : "=v"(d) : "v"(a), "v"(b), "v"(c));
  return d;
#endif
}

// ---------------------------------------------------------------------------
// Kernel 0: pack Wq|Wk|Wv -> bf16 [256][128], biases -> f32 [256].
// ---------------------------------------------------------------------------
__global__ __launch_bounds__(256) void pack_kernel(
    const float* __restrict__ Wq, const float* __restrict__ bq,
    const float* __restrict__ Wk, const float* __restrict__ bk,
    const float* __restrict__ Wv, const float* __restrict__ bv,
    short* __restrict__ wp, float* __restrict__ bp)
{
  const int idx = blockIdx.x * 256 + threadIdx.x;   // 32768
  const int o = idx >> 7, c = idx & 127;
  float v;
  if (o < 64)       v = Wq[o * C_ + c];
  else if (o < 128) v = Wk[(o - 64) * C_ + c];
  else              v = Wv[(o - 128) * C_ + c];
  wp[idx] = f2bf(v);
  if (c == 0)
    bp[o] = (o < 64) ? bq[o] : (o < 128) ? bk[o - 64] : bv[o - 128];
}

// ---------------------------------------------------------------------------
// Kernel 1: QKV 1x1-conv, LDS-staged coalesced outputs.
// Q PRE-SCALED by 0.125*log2(e). qb/kb: [B][N][64] bf16.
// vb: per-32-key-tile images vb[((b*128+T)*8 + key4)*512 + ch*4 + kk].
// grid = B*(N/32) = 512 blocks (each block emits exactly one V tile).
// ---------------------------------------------------------------------------
__global__ __launch_bounds__(256) void qkv_kernel(
    const float* __restrict__ x, const short* __restrict__ wp,
    const float* __restrict__ bp,
    short* __restrict__ qg, short* __restrict__ kg, short* __restrict__ vg)
{
  __shared__ short xT[32 * 136];   // [n][c] bf16, pad 128->136
  __shared__ short outb[256 * 40]; // [o][n] bf16, pad 32->40
  __shared__ float biasL[256];

  const int tid = threadIdx.x;
  const int b   = blockIdx.x >> 7;
  const int n0  = (blockIdx.x & 127) << 5;
  const float QSC = 0.125f * 1.44269504088896340736f;

  biasL[tid] = bp[tid];
  const float* xb = x + (size_t)b * C_ * N_ + n0;
  for (int i = tid; i < 1024; i += 256) {          // 128 c x 8 float4
    const int c = i >> 3, seg = i & 7;
    const float4 v = *(const float4*)&xb[(size_t)c * N_ + seg * 4];
    xT[(seg * 4 + 0) * 136 + c] = f2bf(v.x);
    xT[(seg * 4 + 1) * 136 + c] = f2bf(v.y);
    xT[(seg * 4 + 2) * 136 + c] = f2bf(v.z);
    xT[(seg * 4 + 3) * 136 + c] = f2bf(v.w);
  }
  __syncthreads();

  const int w = tid >> 6, lane = tid & 63, quad = lane >> 4, l16 = lane & 15;

  short8 xf[2][4];
#pragma unroll
  for (int nt = 0; nt < 2; ++nt)
#pragma unroll
    for (int kk = 0; kk < 4; ++kk)
      xf[nt][kk] = *(const short8*)&xT[(nt * 16 + l16) * 136 + kk * 32 + quad * 8];

  if (w < 2) {
    const int obase = w * 64;                      // w0: q (scaled), w1: k
    const float osc = (w == 0) ? QSC : 1.0f;
#pragma unroll
    for (int ot = 0; ot < 4; ++ot) {
      const int o = obase + ot * 16 + l16;
      short8 wf[4];
#pragma unroll
      for (int kk = 0; kk < 4; ++kk)
        wf[kk] = *(const short8*)&wp[(size_t)o * 128 + kk * 32 + quad * 8];
      const float bias = biasL[o];
#pragma unroll
      for (int nt = 0; nt < 2; ++nt) {
        f32x4 acc = (f32x4){0.f, 0.f, 0.f, 0.f};
#pragma unroll
        for (int kk = 0; kk < 4; ++kk)
          acc = __builtin_amdgcn_mfma_f32_16x16x32_bf16(xf[nt][kk], wf[kk], acc, 0, 0, 0);
#pragma unroll
        for (int r = 0; r < 4; ++r)
          outb[o * 40 + nt * 16 + quad * 4 + r] = f2bf((acc[r] + bias) * osc);
      }
    }
  } else {
    const int ob2 = (w - 2) * 64;
#pragma unroll
    for (int ot = 0; ot < 4; ++ot) {
      const int orow = 128 + ob2 + ot * 16 + l16;
      short8 wf[4];
#pragma unroll
      for (int kk = 0; kk < 4; ++kk)
        wf[kk] = *(const short8*)&wp[(size_t)orow * 128 + kk * 32 + quad * 8];
#pragma unroll
      for (int nt = 0; nt < 2; ++nt) {
        f32x4 acc = (f32x4){0.f, 0.f, 0.f, 0.f};
#pragma unroll
        for (int kk = 0; kk < 4; ++kk)
          acc = __builtin_amdgcn_mfma_f32_16x16x32_bf16(wf[kk], xf[nt][kk], acc, 0, 0, 0);
#pragma unroll
        for (int r = 0; r < 4; ++r) {
          const int o_r = 128 + ob2 + ot * 16 + quad * 4 + r;
          outb[o_r * 40 + nt * 16 + l16] = f2bf(acc[r] + biasL[o_r]);
        }
      }
    }
  }
  __syncthreads();

  // q/k coalesced stores: [n][64] rows
  {
    const int n = tid >> 3, oc = tid & 7;
    short8 qv, kv;
#pragma unroll
    for (int j = 0; j < 8; ++j) {
      qv[j] = outb[(oc * 8 + j) * 40 + n];
      kv[j] = outb[(64 + oc * 8 + j) * 40 + n];
    }
    *(short8*)&qg[(((size_t)b * N_ + n0 + n) << 6) + oc * 8] = qv;
    *(short8*)&kg[(((size_t)b * N_ + n0 + n) << 6) + oc * 8] = kv;
  }
  // v tile-image store: this block IS tile T = n0/32 (8 KB contiguous)
  {
    const int T = n0 >> 5;
#pragma unroll
    for (int rep = 0; rep < 2; ++rep) {
      const int idx2 = rep * 256 + tid;            // 0..511
      const int c0  = idx2 & 63;                   // ch-pair
      const int k4l = idx2 >> 6;                   // 0..7
      const bf16x4 lo = *(const bf16x4*)&outb[(128 + 2 * c0) * 40 + k4l * 4];
      const bf16x4 hi = *(const bf16x4*)&outb[(128 + 2 * c0 + 1) * 40 + k4l * 4];
      short8 vv;
#pragma unroll
      for (int j = 0; j < 4; ++j) { vv[j] = lo[j]; vv[4 + j] = hi[j]; }
      const size_t tb = (((size_t)b * 128 + T) * 8 + k4l) * 512 + c0 * 8;
      *(short8*)&vg[tb] = vv;
    }
  }
}

// ---------------------------------------------------------------------------
// Kernel 2: split-K flash attention, S^T trick, KT=32, 24 KiB LDS.
// grid = B*32*SPLITS = 1536 blocks -> EXACTLY 6 blocks/CU (the LDS cap),
// fully resident, 24 waves/CU. Uneven splits over 128 tiles (10 or 11 each).
// Emits Opart [b][s][c][n] bf16 + lbuf f32.
// ---------------------------------------------------------------------------
__global__ __launch_bounds__(256, 4) void attn_kernel(
    const short* __restrict__ qb, const short* __restrict__ kb,
    const short* __restrict__ vb,
    short* __restrict__ Opart, float* __restrict__ lbuf)
{
  __shared__ short kbuf[2][2048];    // 2 x 4 KiB : [key][64ch], 16B-XOR swizzled
  __shared__ short vbuf[2][4096];    // 2 x 8 KiB : tile image [key4][ch][4]

  const int tid = threadIdx.x;
  const int bid = blockIdx.x;
  const int s   = bid % SPLITS;
  const int qt  = (bid / SPLITS) & 31;
  const int b   = bid / (SPLITS * 32);
  const int m0  = qt << 7;
  const int w   = tid >> 6, lane = tid & 63, quad = lane >> 4, l16 = lane & 15;
  const int rbase = m0 + w * 32;

  const int t0  = (s * TT) / SPLITS;
  const int NTs = ((s + 1) * TT) / SPLITS - t0;

  // Q B-fragments [k=ch][n=qrow] (Q pre-scaled at QKV)
  short8 qa[2][2];
#pragma unroll
  for (int mt = 0; mt < 2; ++mt)
#pragma unroll
    for (int kk = 0; kk < 2; ++kk)
      qa[mt][kk] = *(const short8*)&qb[((size_t)b * N_ + rbase + mt * 16 + l16) * 64 + kk * 32 + quad * 8];

  float lsum[2] = {0.f, 0.f};
  f32x4 accO[8][2];                  // O^T [ch-tile][qrow-tile]
#pragma unroll
  for (int vt = 0; vt < 8; ++vt)
#pragma unroll
    for (int mt = 0; mt < 2; ++mt) accO[vt][mt] = (f32x4){0.f, 0.f, 0.f, 0.f};

  auto dma_tile = [&](int kt, int d) {
    const int T = t0 + kt;
    const short* kbp = kb + (((size_t)b * N_ + T * 32) << 6);
    {                                // K: 256 x 16B chunks, XOR-swizzled
      const int p = w * 64 + lane;
      const int key = p >> 3, jm = (p & 7) ^ (key & 7);
      __builtin_amdgcn_global_load_lds((gp_t)(kbp + (key << 6) + jm * 8),
                                       (lp_t)&kbuf[d][w * 512], 16, 0, 0);
    }
    const short* vtp = vb + ((size_t)b * 128 + T) * 4096;
#pragma unroll
    for (int t = 0; t < 2; ++t) {    // V: 512 x 16B chunks, LINEAR image copy
      const int p = (w * 2 + t) * 64 + lane;
      __builtin_amdgcn_global_load_lds((gp_t)(vtp + p * 8),
                                       (lp_t)&vbuf[d][(w * 2 + t) * 512], 16, 0, 0);
    }
  };

  dma_tile(0, 0);

  for (int kt = 0; kt < NTs; ++kt) {
    __syncthreads();                 // drains this tile's DMA on all waves
    if (kt + 1 < NTs) dma_tile(kt + 1, (kt + 1) & 1);
    const int d = kt & 1;

    // ---- S^T = K Q^T : 2 key-subtiles of 16, K-dim 64 = 2 MFMA steps ----
    bf16x4 pbf[2][2];                // P^T B-frags for K=16 PV
#pragma unroll
    for (int ct = 0; ct < 2; ++ct) {
      const short8 kf0 = *(const short8*)&kbuf[d][((ct * 16 + l16) << 6) + ((quad ^ (l16 & 7)) << 3)];
      const short8 kf1 = *(const short8*)&kbuf[d][((ct * 16 + l16) << 6) + (((4 + quad) ^ (l16 & 7)) << 3)];
#pragma unroll
      for (int mt = 0; mt < 2; ++mt) {
        f32x4 st = (f32x4){0.f, 0.f, 0.f, 0.f};
        st = __builtin_amdgcn_mfma_f32_16x16x32_bf16(kf0, qa[mt][0], st, 0, 0, 0);
        st = __builtin_amdgcn_mfma_f32_16x16x32_bf16(kf1, qa[mt][1], st, 0, 0, 0);
        const float p0 = fexp2(st[0]);
        const float p1 = fexp2(st[1]);
        const float p2 = fexp2(st[2]);
        const float p3 = fexp2(st[3]);
        lsum[mt] += (p0 + p1) + (p2 + p3);
        u32x2 pp;
        pp[0] = pk2(p0, p1);
        pp[1] = pk2(p2, p3);
        pbf[ct][mt] = __builtin_bit_cast(bf16x4, pp);   // B[k=quad*4+r][n=l16]
      }
    }

    // ---- O^T += V^T P^T : conflict-free b64 A-frag reads ----
#pragma unroll
    for (int vt = 0; vt < 8; ++vt) {
#pragma unroll
      for (int ct = 0; ct < 2; ++ct) {
        const bf16x4 vf = *(const bf16x4*)&vbuf[d][(ct * 4 + quad) * 512 + (vt * 16 + l16) * 4];
        accO[vt][0] = mfma16(vf, pbf[ct][0], accO[vt][0]);
        accO[vt][1] = mfma16(vf, pbf[ct][1], accO[vt][1]);
      }
    }
  }

  // ---- epilogue: reduce l across quads; store O^T + l ----
#pragma unroll
  for (int mt = 0; mt < 2; ++mt) {
    lsum[mt] += __shfl_xor(lsum[mt], 16);
    lsum[mt] += __shfl_xor(lsum[mt], 32);
  }
  if (quad == 0) {
#pragma unroll
    for (int mt = 0; mt < 2; ++mt)
      lbuf[((size_t)b * SPLITS + s) * N_ + rbase + mt * 16 + l16] = lsum[mt];
  }
#pragma unroll
  for (int vt = 0; vt < 8; ++vt) {
#pragma unroll
    for (int mt = 0; mt < 2; ++mt) {
#pragma unroll
      for (int r = 0; r < 4; ++r) {
        const int ch = vt * 16 + quad * 4 + r;
        Opart[(((size_t)b * SPLITS + s) * C_ + ch) * N_ + rbase + mt * 16 + l16] =
            f2bf(accO[vt][mt][r]);
      }
    }
  }
}

// ---------------------------------------------------------------------------
// Kernel 3: combine splits + residual, linv computed in-block.
// grid = B * (N/64) = 256 blocks; block = 64 n x 128 c.
// ---------------------------------------------------------------------------
__global__ __launch_bounds__(256) void combine_kernel(
    const float* __restrict__ x, const float* __restrict__ gamma,
    const short* __restrict__ Opart, const float* __restrict__ lbuf,
    float* __restrict__ out)
{
  __shared__ float linvL[64];
  const int tid = threadIdx.x;
  const int b   = blockIdx.x >> 6;
  const int n0  = (blockIdx.x & 63) << 6;

  if (tid < 64) {
    float L = 0.f;
#pragma unroll
    for (int s = 0; s < SPLITS; ++s) L += lbuf[((size_t)b * SPLITS + s) * N_ + n0 + tid];
    linvL[tid] = 1.f / L;
  }
  __syncthreads();

  const float g = gamma[0];
  const int n4 = (tid & 15) * 4, cb = tid >> 4;    // cb 0..15
#pragma unroll
  for (int cp = 0; cp < 8; ++cp) {
    const int c = cp * 16 + cb;
    float acc[4] = {0.f, 0.f, 0.f, 0.f};
#pragma unroll
    for (int s = 0; s < SPLITS; ++s) {
      const bf16x4 o4 = *(const bf16x4*)&Opart[(((size_t)b * SPLITS + s) * C_ + c) * N_ + n0 + n4];
#pragma unroll
      for (int j = 0; j < 4; ++j) acc[j] += bf2f(o4[j]);
    }
    const size_t xi = ((size_t)b * C_ + c) * N_ + n0 + n4;
    const float4 xv = *(const float4*)&x[xi];
    float4 ov;
    ov.x = xv.x + g * acc[0] * linvL[n4 + 0];
    ov.y = xv.y + g * acc[1] * linvL[n4 + 1];
    ov.z = xv.z + g * acc[2] * linvL[n4 + 2];
    ov.w = xv.w + g * acc[3] * linvL[n4 + 3];
    *(float4*)&out[xi] = ov;
  }
}

// ---------------------------------------------------------------------------
extern "C" void kernel_launch(void* const* d_in, const int* in_sizes, int n_in,
                              void* d_out, int out_size, void* d_ws, size_t ws_size,
                              hipStream_t stream) {
  const float* x     = (const float*)d_in[0];
  const float* Wq    = (const float*)d_in[1];
  const float* bq    = (const float*)d_in[2];
  const float* Wk    = (const float*)d_in[3];
  const float* bk    = (const float*)d_in[4];
  const float* Wv    = (const float*)d_in[5];
  const float* bv    = (const float*)d_in[6];
  const float* gamma = (const float*)d_in[7];
  float* out = (float*)d_out;

  short* qb = (short*)d_ws;                          // [4][4096][64]  bf16 = 2 MB
  short* kb = qb + (size_t)B_ * N_ * INNER_;         // [4][4096][64]  bf16 = 2 MB
  short* vb = kb + (size_t)B_ * N_ * INNER_;         // tile-imaged V  bf16 = 4 MB
  short* Opart = vb + (size_t)B_ * C_ * N_;          // [4][12][128][4096] bf16 = 48 MB
  float* lbuf  = (float*)(Opart + (size_t)B_ * SPLITS * C_ * N_); // [4][12][4096] f32
  float* bp    = lbuf + (size_t)B_ * SPLITS * N_;    // [256] f32
  short* wp    = (short*)(bp + 256);                 // [256][128] bf16

  pack_kernel<<<128, 256, 0, stream>>>(Wq, bq, Wk, bk, Wv, bv, wp, bp);
  qkv_kernel<<<B_ * (N_ / 32), 256, 0, stream>>>(x, wp, bp, qb, kb, vb);
  attn_kernel<<<B_ * 32 * SPLITS, 256, 0, stream>>>(qb, kb, vb, Opart, lbuf);
  combine_kernel<<<B_ * (N_ / 64), 256, 0, stream>>>(x, gamma, Opart, lbuf, out);
}

// Round 10
// 126.710 us; speedup vs baseline: 1.0148x; 1.0148x over previous
//
#include <hip/hip_runtime.h>
#include <cstdint>

#define B_ 4
#define C_ 128
#define INNER_ 64
#define N_ 4096
#define SPLITS 12                 // key-dimension splits (uneven, tile-granular)
#define KT 32                     // key-tile size
#define TT 128                    // total key tiles = N_/KT

typedef __attribute__((ext_vector_type(8))) short short8;
typedef __attribute__((ext_vector_type(4))) short bf16x4;
typedef __attribute__((ext_vector_type(4))) float f32x4;
typedef __attribute__((ext_vector_type(2))) unsigned u32x2;
typedef __attribute__((ext_vector_type(4))) unsigned u32x4;

typedef const __attribute__((address_space(1))) void* gp_t;
typedef __attribute__((address_space(3))) void* lp_t;

__device__ __forceinline__ short f2bf(float f) {
  unsigned u = __builtin_bit_cast(unsigned, f);
  unsigned r = (u + 0x7FFFu + ((u >> 16) & 1u)) >> 16;
  return (short)r;
}
__device__ __forceinline__ float bf2f(short s) {
  return __builtin_bit_cast(float, ((unsigned)(unsigned short)s) << 16);
}
__device__ __forceinline__ float fexp2(float x) {
#if __has_builtin(__builtin_amdgcn_exp2f)
  return __builtin_amdgcn_exp2f(x);
#else
  return exp2f(x);
#endif
}
__device__ __forceinline__ unsigned pk2(float lo, float hi) {
#if __has_builtin(__builtin_amdgcn_cvt_pk_bf16_f32)
  typedef __attribute__((ext_vector_type(2))) __bf16 bfp;
  bfp v = __builtin_amdgcn_cvt_pk_bf16_f32(lo, hi);
  return __builtin_bit_cast(unsigned, v);
#else
  return (unsigned)(unsigned short)f2bf(lo) | ((unsigned)(unsigned short)f2bf(hi) << 16);
#endif
}

// ---------------------------------------------------------------------------
// Kernel 0: pack Wq|Wk|Wv -> bf16 [256][128], biases -> f32 [256].
// ---------------------------------------------------------------------------
__global__ __launch_bounds__(256) void pack_kernel(
    const float* __restrict__ Wq, const float* __restrict__ bq,
    const float* __restrict__ Wk, const float* __restrict__ bk,
    const float* __restrict__ Wv, const float* __restrict__ bv,
    short* __restrict__ wp, float* __restrict__ bp)
{
  const int idx = blockIdx.x * 256 + threadIdx.x;   // 32768
  const int o = idx >> 7, c = idx & 127;
  float v;
  if (o < 64)       v = Wq[o * C_ + c];
  else if (o < 128) v = Wk[(o - 64) * C_ + c];
  else              v = Wv[(o - 128) * C_ + c];
  wp[idx] = f2bf(v);
  if (c == 0)
    bp[o] = (o < 64) ? bq[o] : (o < 128) ? bk[o - 64] : bv[o - 128];
}

// ---------------------------------------------------------------------------
// Kernel 1: QKV 1x1-conv, LDS-staged coalesced outputs.
// Q PRE-SCALED by 0.125*log2(e). qb/kb: [B][N][64] bf16.
// vb: per-32-key-tile PERMUTED images:
//   vimg[b][T][ch][quad][e], e=0..7 holds key_local = (e>>2)*16 + quad*4 + (e&3)
// so P^T's native S-output register order is a valid K=32 B-frag.
// grid = B*(N/32) = 512 blocks (each block emits exactly one V tile).
// ---------------------------------------------------------------------------
__global__ __launch_bounds__(256) void qkv_kernel(
    const float* __restrict__ x, const short* __restrict__ wp,
    const float* __restrict__ bp,
    short* __restrict__ qg, short* __restrict__ kg, short* __restrict__ vg)
{
  __shared__ short xT[32 * 136];   // [n][c] bf16, pad 128->136
  __shared__ short outb[256 * 40]; // [o][n] bf16, pad 32->40
  __shared__ float biasL[256];

  const int tid = threadIdx.x;
  const int b   = blockIdx.x >> 7;
  const int n0  = (blockIdx.x & 127) << 5;
  const float QSC = 0.125f * 1.44269504088896340736f;

  biasL[tid] = bp[tid];
  const float* xb = x + (size_t)b * C_ * N_ + n0;
  for (int i = tid; i < 1024; i += 256) {          // 128 c x 8 float4
    const int c = i >> 3, seg = i & 7;
    const float4 v = *(const float4*)&xb[(size_t)c * N_ + seg * 4];
    xT[(seg * 4 + 0) * 136 + c] = f2bf(v.x);
    xT[(seg * 4 + 1) * 136 + c] = f2bf(v.y);
    xT[(seg * 4 + 2) * 136 + c] = f2bf(v.z);
    xT[(seg * 4 + 3) * 136 + c] = f2bf(v.w);
  }
  __syncthreads();

  const int w = tid >> 6, lane = tid & 63, quad = lane >> 4, l16 = lane & 15;

  short8 xf[2][4];
#pragma unroll
  for (int nt = 0; nt < 2; ++nt)
#pragma unroll
    for (int kk = 0; kk < 4; ++kk)
      xf[nt][kk] = *(const short8*)&xT[(nt * 16 + l16) * 136 + kk * 32 + quad * 8];

  if (w < 2) {
    const int obase = w * 64;                      // w0: q (scaled), w1: k
    const float osc = (w == 0) ? QSC : 1.0f;
#pragma unroll
    for (int ot = 0; ot < 4; ++ot) {
      const int o = obase + ot * 16 + l16;
      short8 wf[4];
#pragma unroll
      for (int kk = 0; kk < 4; ++kk)
        wf[kk] = *(const short8*)&wp[(size_t)o * 128 + kk * 32 + quad * 8];
      const float bias = biasL[o];
#pragma unroll
      for (int nt = 0; nt < 2; ++nt) {
        f32x4 acc = (f32x4){0.f, 0.f, 0.f, 0.f};
#pragma unroll
        for (int kk = 0; kk < 4; ++kk)
          acc = __builtin_amdgcn_mfma_f32_16x16x32_bf16(xf[nt][kk], wf[kk], acc, 0, 0, 0);
#pragma unroll
        for (int r = 0; r < 4; ++r)
          outb[o * 40 + nt * 16 + quad * 4 + r] = f2bf((acc[r] + bias) * osc);
      }
    }
  } else {
    const int ob2 = (w - 2) * 64;
#pragma unroll
    for (int ot = 0; ot < 4; ++ot) {
      const int orow = 128 + ob2 + ot * 16 + l16;
      short8 wf[4];
#pragma unroll
      for (int kk = 0; kk < 4; ++kk)
        wf[kk] = *(const short8*)&wp[(size_t)orow * 128 + kk * 32 + quad * 8];
#pragma unroll
      for (int nt = 0; nt < 2; ++nt) {
        f32x4 acc = (f32x4){0.f, 0.f, 0.f, 0.f};
#pragma unroll
        for (int kk = 0; kk < 4; ++kk)
          acc = __builtin_amdgcn_mfma_f32_16x16x32_bf16(wf[kk], xf[nt][kk], acc, 0, 0, 0);
#pragma unroll
        for (int r = 0; r < 4; ++r) {
          const int o_r = 128 + ob2 + ot * 16 + quad * 4 + r;
          outb[o_r * 40 + nt * 16 + l16] = f2bf(acc[r] + biasL[o_r]);
        }
      }
    }
  }
  __syncthreads();

  // q/k coalesced stores: [n][64] rows
  {
    const int n = tid >> 3, oc = tid & 7;
    short8 qv, kv;
#pragma unroll
    for (int j = 0; j < 8; ++j) {
      qv[j] = outb[(oc * 8 + j) * 40 + n];
      kv[j] = outb[(64 + oc * 8 + j) * 40 + n];
    }
    *(short8*)&qg[(((size_t)b * N_ + n0 + n) << 6) + oc * 8] = qv;
    *(short8*)&kg[(((size_t)b * N_ + n0 + n) << 6) + oc * 8] = kv;
  }
  // v permuted tile-image store: this block IS tile T = n0/32 (8 KB contiguous)
  // chunk idx2: ch = idx2>>2, q = idx2&3; 16B = keys {q*4..+3, 16+q*4..+3}
  {
    const int T = n0 >> 5;
#pragma unroll
    for (int rep = 0; rep < 2; ++rep) {
      const int idx2 = rep * 256 + tid;            // 0..511
      const int ch = idx2 >> 2, q = idx2 & 3;
      const bf16x4 lo = *(const bf16x4*)&outb[(128 + ch) * 40 + q * 4];
      const bf16x4 hi = *(const bf16x4*)&outb[(128 + ch) * 40 + 16 + q * 4];
      short8 vv;
#pragma unroll
      for (int j = 0; j < 4; ++j) { vv[j] = lo[j]; vv[4 + j] = hi[j]; }
      const size_t tb = ((size_t)b * 128 + T) * 4096 + (size_t)idx2 * 8;
      *(short8*)&vg[tb] = vv;
    }
  }
}

// ---------------------------------------------------------------------------
// Kernel 2: split-K flash attention. S^T trick + PERMUTED-V K=32 PV:
// per wave-iter only 24 MFMA (all 16x16x32) + 12 ds_read_b128, all
// conflict-free. KT=32, 24 KiB LDS, grid = B*32*SPLITS = 1536 blocks ->
// 6 blocks/CU fully resident. Emits Opart [b][s][c][n] bf16 + lbuf f32.
// ---------------------------------------------------------------------------
__global__ __launch_bounds__(256, 4) void attn_kernel(
    const short* __restrict__ qb, const short* __restrict__ kb,
    const short* __restrict__ vb,
    short* __restrict__ Opart, float* __restrict__ lbuf)
{
  __shared__ short kbuf[2][2048];    // 2 x 4 KiB : [key][64ch], 16B-XOR swizzled
  __shared__ short vbuf[2][4096];    // 2 x 8 KiB : permuted image [ch][quad][8]

  const int tid = threadIdx.x;
  const int bid = blockIdx.x;
  const int s   = bid % SPLITS;
  const int qt  = (bid / SPLITS) & 31;
  const int b   = bid / (SPLITS * 32);
  const int m0  = qt << 7;
  const int w   = tid >> 6, lane = tid & 63, quad = lane >> 4, l16 = lane & 15;
  const int rbase = m0 + w * 32;

  const int t0  = (s * TT) / SPLITS;
  const int NTs = ((s + 1) * TT) / SPLITS - t0;

  // Q B-fragments [k=ch][n=qrow] (Q pre-scaled at QKV)
  short8 qa[2][2];
#pragma unroll
  for (int mt = 0; mt < 2; ++mt)
#pragma unroll
    for (int kk = 0; kk < 2; ++kk)
      qa[mt][kk] = *(const short8*)&qb[((size_t)b * N_ + rbase + mt * 16 + l16) * 64 + kk * 32 + quad * 8];

  float lsum[2] = {0.f, 0.f};
  f32x4 accO[8][2];                  // O^T [ch-tile][qrow-tile]
#pragma unroll
  for (int vt = 0; vt < 8; ++vt)
#pragma unroll
    for (int mt = 0; mt < 2; ++mt) accO[vt][mt] = (f32x4){0.f, 0.f, 0.f, 0.f};

  auto dma_tile = [&](int kt, int d) {
    const int T = t0 + kt;
    const short* kbp = kb + (((size_t)b * N_ + T * 32) << 6);
    {                                // K: 256 x 16B chunks, XOR-swizzled
      const int p = w * 64 + lane;
      const int key = p >> 3, jm = (p & 7) ^ (key & 7);
      __builtin_amdgcn_global_load_lds((gp_t)(kbp + (key << 6) + jm * 8),
                                       (lp_t)&kbuf[d][w * 512], 16, 0, 0);
    }
    const short* vtp = vb + ((size_t)b * 128 + T) * 4096;
#pragma unroll
    for (int t = 0; t < 2; ++t) {    // V: 512 x 16B chunks, LINEAR image copy
      const int p = (w * 2 + t) * 64 + lane;
      __builtin_amdgcn_global_load_lds((gp_t)(vtp + p * 8),
                                       (lp_t)&vbuf[d][(w * 2 + t) * 512], 16, 0, 0);
    }
  };

  dma_tile(0, 0);

  for (int kt = 0; kt < NTs; ++kt) {
    __syncthreads();                 // drains this tile's DMA on all waves
    if (kt + 1 < NTs) dma_tile(kt + 1, (kt + 1) & 1);
    const int d = kt & 1;

    // ---- S^T = K Q^T : 2 key-subtiles of 16, K-dim 64 = 2 MFMA steps ----
    u32x2 ppk[2][2];                 // [ct][mt] packed P (keys ct*16+quad*4+r)
#pragma unroll
    for (int ct = 0; ct < 2; ++ct) {
      const short8 kf0 = *(const short8*)&kbuf[d][((ct * 16 + l16) << 6) + ((quad ^ (l16 & 7)) << 3)];
      const short8 kf1 = *(const short8*)&kbuf[d][((ct * 16 + l16) << 6) + (((4 + quad) ^ (l16 & 7)) << 3)];
#pragma unroll
      for (int mt = 0; mt < 2; ++mt) {
        f32x4 st = (f32x4){0.f, 0.f, 0.f, 0.f};
        st = __builtin_amdgcn_mfma_f32_16x16x32_bf16(kf0, qa[mt][0], st, 0, 0, 0);
        st = __builtin_amdgcn_mfma_f32_16x16x32_bf16(kf1, qa[mt][1], st, 0, 0, 0);
        const float p0 = fexp2(st[0]);
        const float p1 = fexp2(st[1]);
        const float p2 = fexp2(st[2]);
        const float p3 = fexp2(st[3]);
        lsum[mt] += (p0 + p1) + (p2 + p3);
        u32x2 pp;
        pp[0] = pk2(p0, p1);
        pp[1] = pk2(p2, p3);
        ppk[ct][mt] = pp;
      }
    }
    // concat ct0|ct1 -> valid K=32 B-frag under the V key-permutation
    short8 pcat[2];
#pragma unroll
    for (int mt = 0; mt < 2; ++mt) {
      u32x4 u = (u32x4){ppk[0][mt][0], ppk[0][mt][1], ppk[1][mt][0], ppk[1][mt][1]};
      pcat[mt] = __builtin_bit_cast(short8, u);
    }

    // ---- O^T += V^T P^T : K=32, A-frag = single conflict-free b128 ----
#pragma unroll
    for (int vt = 0; vt < 8; ++vt) {
      const short8 vf = *(const short8*)&vbuf[d][((vt * 16 + l16) << 5) + (quad << 3)];
      accO[vt][0] = __builtin_amdgcn_mfma_f32_16x16x32_bf16(vf, pcat[0], accO[vt][0], 0, 0, 0);
      accO[vt][1] = __builtin_amdgcn_mfma_f32_16x16x32_bf16(vf, pcat[1], accO[vt][1], 0, 0, 0);
    }
  }

  // ---- epilogue: reduce l across quads; store O^T + l ----
#pragma unroll
  for (int mt = 0; mt < 2; ++mt) {
    lsum[mt] += __shfl_xor(lsum[mt], 16);
    lsum[mt] += __shfl_xor(lsum[mt], 32);
  }
  if (quad == 0) {
#pragma unroll
    for (int mt = 0; mt < 2; ++mt)
      lbuf[((size_t)b * SPLITS + s) * N_ + rbase + mt * 16 + l16] = lsum[mt];
  }
#pragma unroll
  for (int vt = 0; vt < 8; ++vt) {
#pragma unroll
    for (int mt = 0; mt < 2; ++mt) {
#pragma unroll
      for (int r = 0; r < 4; ++r) {
        const int ch = vt * 16 + quad * 4 + r;
        Opart[(((size_t)b * SPLITS + s) * C_ + ch) * N_ + rbase + mt * 16 + l16] =
            f2bf(accO[vt][mt][r]);
      }
    }
  }
}

// ---------------------------------------------------------------------------
// Kernel 3: combine splits + residual, linv computed in-block.
// grid = B * (N/64) = 256 blocks; block = 64 n x 128 c.
// ---------------------------------------------------------------------------
__global__ __launch_bounds__(256) void combine_kernel(
    const float* __restrict__ x, const float* __restrict__ gamma,
    const short* __restrict__ Opart, const float* __restrict__ lbuf,
    float* __restrict__ out)
{
  __shared__ float linvL[64];
  const int tid = threadIdx.x;
  const int b   = blockIdx.x >> 6;
  const int n0  = (blockIdx.x & 63) << 6;

  if (tid < 64) {
    float L = 0.f;
#pragma unroll
    for (int s = 0; s < SPLITS; ++s) L += lbuf[((size_t)b * SPLITS + s) * N_ + n0 + tid];
    linvL[tid] = 1.f / L;
  }
  __syncthreads();

  const float g = gamma[0];
  const int n4 = (tid & 15) * 4, cb = tid >> 4;    // cb 0..15
#pragma unroll
  for (int cp = 0; cp < 8; ++cp) {
    const int c = cp * 16 + cb;
    float acc[4] = {0.f, 0.f, 0.f, 0.f};
#pragma unroll
    for (int s = 0; s < SPLITS; ++s) {
      const bf16x4 o4 = *(const bf16x4*)&Opart[(((size_t)b * SPLITS + s) * C_ + c) * N_ + n0 + n4];
#pragma unroll
      for (int j = 0; j < 4; ++j) acc[j] += bf2f(o4[j]);
    }
    const size_t xi = ((size_t)b * C_ + c) * N_ + n0 + n4;
    const float4 xv = *(const float4*)&x[xi];
    float4 ov;
    ov.x = xv.x + g * acc[0] * linvL[n4 + 0];
    ov.y = xv.y + g * acc[1] * linvL[n4 + 1];
    ov.z = xv.z + g * acc[2] * linvL[n4 + 2];
    ov.w = xv.w + g * acc[3] * linvL[n4 + 3];
    *(float4*)&out[xi] = ov;
  }
}

// ---------------------------------------------------------------------------
extern "C" void kernel_launch(void* const* d_in, const int* in_sizes, int n_in,
                              void* d_out, int out_size, void* d_ws, size_t ws_size,
                              hipStream_t stream) {
  const float* x     = (const float*)d_in[0];
  const float* Wq    = (const float*)d_in[1];
  const float* bq    = (const float*)d_in[2];
  const float* Wk    = (const float*)d_in[3];
  const float* bk    = (const float*)d_in[4];
  const float* Wv    = (const float*)d_in[5];
  const float* bv    = (const float*)d_in[6];
  const float* gamma = (const float*)d_in[7];
  float* out = (float*)d_out;

  short* qb = (short*)d_ws;                          // [4][4096][64]  bf16 = 2 MB
  short* kb = qb + (size_t)B_ * N_ * INNER_;         // [4][4096][64]  bf16 = 2 MB
  short* vb = kb + (size_t)B_ * N_ * INNER_;         // permuted V images = 4 MB
  short* Opart = vb + (size_t)B_ * C_ * N_;          // [4][12][128][4096] bf16 = 48 MB
  float* lbuf  = (float*)(Opart + (size_t)B_ * SPLITS * C_ * N_); // [4][12][4096] f32
  float* bp    = lbuf + (size_t)B_ * SPLITS * N_;    // [256] f32
  short* wp    = (short*)(bp + 256);                 // [256][128] bf16

  pack_kernel<<<128, 256, 0, stream>>>(Wq, bq, Wk, bk, Wv, bv, wp, bp);
  qkv_kernel<<<B_ * (N_ / 32), 256, 0, stream>>>(x, wp, bp, qb, kb, vb);
  attn_kernel<<<B_ * 32 * SPLITS, 256, 0, stream>>>(qb, kb, vb, Opart, lbuf);
  combine_kernel<<<B_ * (N_ / 64), 256, 0, stream>>>(x, gamma, Opart, lbuf, out);
}

// Round 11
// 124.246 us; speedup vs baseline: 1.0350x; 1.0198x over previous
//
#include <hip/hip_runtime.h>
#include <cstdint>

#define B_ 4
#define C_ 128
#define INNER_ 64
#define N_ 4096
#define SPLITS 8                  // key-dimension splits
#define KT 32                     // key-tile size
#define NTS 16                    // tiles per split = (N/SPLITS)/KT

typedef __attribute__((ext_vector_type(8))) short short8;
typedef __attribute__((ext_vector_type(4))) short bf16x4;
typedef __attribute__((ext_vector_type(4))) float f32x4;
typedef __attribute__((ext_vector_type(2))) unsigned u32x2;
typedef __attribute__((ext_vector_type(4))) unsigned u32x4;

typedef const __attribute__((address_space(1))) void* gp_t;
typedef __attribute__((address_space(3))) void* lp_t;

__device__ __forceinline__ short f2bf(float f) {
  unsigned u = __builtin_bit_cast(unsigned, f);
  unsigned r = (u + 0x7FFFu + ((u >> 16) & 1u)) >> 16;
  return (short)r;
}
__device__ __forceinline__ float bf2f(short s) {
  return __builtin_bit_cast(float, ((unsigned)(unsigned short)s) << 16);
}
__device__ __forceinline__ float fexp2(float x) {
#if __has_builtin(__builtin_amdgcn_exp2f)
  return __builtin_amdgcn_exp2f(x);
#else
  return exp2f(x);
#endif
}
__device__ __forceinline__ unsigned pk2(float lo, float hi) {
#if __has_builtin(__builtin_amdgcn_cvt_pk_bf16_f32)
  typedef __attribute__((ext_vector_type(2))) __bf16 bfp;
  bfp v = __builtin_amdgcn_cvt_pk_bf16_f32(lo, hi);
  return __builtin_bit_cast(unsigned, v);
#else
  return (unsigned)(unsigned short)f2bf(lo) | ((unsigned)(unsigned short)f2bf(hi) << 16);
#endif
}

// ---------------------------------------------------------------------------
// Kernel 0: pack Wq|Wk|Wv -> bf16 [256][128], biases -> f32 [256].
// ---------------------------------------------------------------------------
__global__ __launch_bounds__(256) void pack_kernel(
    const float* __restrict__ Wq, const float* __restrict__ bq,
    const float* __restrict__ Wk, const float* __restrict__ bk,
    const float* __restrict__ Wv, const float* __restrict__ bv,
    short* __restrict__ wp, float* __restrict__ bp)
{
  const int idx = blockIdx.x * 256 + threadIdx.x;   // 32768
  const int o = idx >> 7, c = idx & 127;
  float v;
  if (o < 64)       v = Wq[o * C_ + c];
  else if (o < 128) v = Wk[(o - 64) * C_ + c];
  else              v = Wv[(o - 128) * C_ + c];
  wp[idx] = f2bf(v);
  if (c == 0)
    bp[o] = (o < 64) ? bq[o] : (o < 128) ? bk[o - 64] : bv[o - 128];
}

// ---------------------------------------------------------------------------
// Kernel 1: QKV 1x1-conv, LDS-staged coalesced outputs (unchanged from R10).
// Q PRE-SCALED by 0.125*log2(e). qb/kb: [B][N][64] bf16.
// vb: per-32-key-tile PERMUTED images:
//   vimg[b][T][ch][quad][e], e=0..7 holds key_local = (e>>2)*16 + quad*4 + (e&3)
// grid = B*(N/32) = 512 blocks (each block emits exactly one V tile).
// ---------------------------------------------------------------------------
__global__ __launch_bounds__(256) void qkv_kernel(
    const float* __restrict__ x, const short* __restrict__ wp,
    const float* __restrict__ bp,
    short* __restrict__ qg, short* __restrict__ kg, short* __restrict__ vg)
{
  __shared__ short xT[32 * 136];   // [n][c] bf16, pad 128->136
  __shared__ short outb[256 * 40]; // [o][n] bf16, pad 32->40
  __shared__ float biasL[256];

  const int tid = threadIdx.x;
  const int b   = blockIdx.x >> 7;
  const int n0  = (blockIdx.x & 127) << 5;
  const float QSC = 0.125f * 1.44269504088896340736f;

  biasL[tid] = bp[tid];
  const float* xb = x + (size_t)b * C_ * N_ + n0;
  for (int i = tid; i < 1024; i += 256) {          // 128 c x 8 float4
    const int c = i >> 3, seg = i & 7;
    const float4 v = *(const float4*)&xb[(size_t)c * N_ + seg * 4];
    xT[(seg * 4 + 0) * 136 + c] = f2bf(v.x);
    xT[(seg * 4 + 1) * 136 + c] = f2bf(v.y);
    xT[(seg * 4 + 2) * 136 + c] = f2bf(v.z);
    xT[(seg * 4 + 3) * 136 + c] = f2bf(v.w);
  }
  __syncthreads();

  const int w = tid >> 6, lane = tid & 63, quad = lane >> 4, l16 = lane & 15;

  short8 xf[2][4];
#pragma unroll
  for (int nt = 0; nt < 2; ++nt)
#pragma unroll
    for (int kk = 0; kk < 4; ++kk)
      xf[nt][kk] = *(const short8*)&xT[(nt * 16 + l16) * 136 + kk * 32 + quad * 8];

  if (w < 2) {
    const int obase = w * 64;                      // w0: q (scaled), w1: k
    const float osc = (w == 0) ? QSC : 1.0f;
#pragma unroll
    for (int ot = 0; ot < 4; ++ot) {
      const int o = obase + ot * 16 + l16;
      short8 wf[4];
#pragma unroll
      for (int kk = 0; kk < 4; ++kk)
        wf[kk] = *(const short8*)&wp[(size_t)o * 128 + kk * 32 + quad * 8];
      const float bias = biasL[o];
#pragma unroll
      for (int nt = 0; nt < 2; ++nt) {
        f32x4 acc = (f32x4){0.f, 0.f, 0.f, 0.f};
#pragma unroll
        for (int kk = 0; kk < 4; ++kk)
          acc = __builtin_amdgcn_mfma_f32_16x16x32_bf16(xf[nt][kk], wf[kk], acc, 0, 0, 0);
#pragma unroll
        for (int r = 0; r < 4; ++r)
          outb[o * 40 + nt * 16 + quad * 4 + r] = f2bf((acc[r] + bias) * osc);
      }
    }
  } else {
    const int ob2 = (w - 2) * 64;
#pragma unroll
    for (int ot = 0; ot < 4; ++ot) {
      const int orow = 128 + ob2 + ot * 16 + l16;
      short8 wf[4];
#pragma unroll
      for (int kk = 0; kk < 4; ++kk)
        wf[kk] = *(const short8*)&wp[(size_t)orow * 128 + kk * 32 + quad * 8];
#pragma unroll
      for (int nt = 0; nt < 2; ++nt) {
        f32x4 acc = (f32x4){0.f, 0.f, 0.f, 0.f};
#pragma unroll
        for (int kk = 0; kk < 4; ++kk)
          acc = __builtin_amdgcn_mfma_f32_16x16x32_bf16(wf[kk], xf[nt][kk], acc, 0, 0, 0);
#pragma unroll
        for (int r = 0; r < 4; ++r) {
          const int o_r = 128 + ob2 + ot * 16 + quad * 4 + r;
          outb[o_r * 40 + nt * 16 + l16] = f2bf(acc[r] + biasL[o_r]);
        }
      }
    }
  }
  __syncthreads();

  // q/k coalesced stores: [n][64] rows
  {
    const int n = tid >> 3, oc = tid & 7;
    short8 qv, kv;
#pragma unroll
    for (int j = 0; j < 8; ++j) {
      qv[j] = outb[(oc * 8 + j) * 40 + n];
      kv[j] = outb[(64 + oc * 8 + j) * 40 + n];
    }
    *(short8*)&qg[(((size_t)b * N_ + n0 + n) << 6) + oc * 8] = qv;
    *(short8*)&kg[(((size_t)b * N_ + n0 + n) << 6) + oc * 8] = kv;
  }
  // v permuted tile-image store: this block IS tile T = n0/32 (8 KB contiguous)
  {
    const int T = n0 >> 5;
#pragma unroll
    for (int rep = 0; rep < 2; ++rep) {
      const int idx2 = rep * 256 + tid;            // 0..511
      const int ch = idx2 >> 2, q = idx2 & 3;
      const bf16x4 lo = *(const bf16x4*)&outb[(128 + ch) * 40 + q * 4];
      const bf16x4 hi = *(const bf16x4*)&outb[(128 + ch) * 40 + 16 + q * 4];
      short8 vv;
#pragma unroll
      for (int j = 0; j < 4; ++j) { vv[j] = lo[j]; vv[4 + j] = hi[j]; }
      const size_t tb = ((size_t)b * 128 + T) * 4096 + (size_t)idx2 * 8;
      *(short8*)&vg[tb] = vv;
    }
  }
}

// ---------------------------------------------------------------------------
// Kernel 2: split-K flash attention. WAVE = 64 Q-ROWS (4 row-tiles):
// halves the total wave-iteration count (the empirically binding quantum).
// S^T trick + permuted-V K=32 PV, KT=32, 24 KiB LDS.
// block = 4 waves = 256 q-rows; grid = B*16*SPLITS = 512 blocks -> 2/CU.
// Emits Opart [b][s][c][n] bf16 + lbuf f32.
// ---------------------------------------------------------------------------
__global__ __launch_bounds__(256, 2) void attn_kernel(
    const short* __restrict__ qb, const short* __restrict__ kb,
    const short* __restrict__ vb,
    short* __restrict__ Opart, float* __restrict__ lbuf)
{
  __shared__ short kbuf[2][2048];    // 2 x 4 KiB : [key][64ch], 16B-XOR swizzled
  __shared__ short vbuf[2][4096];    // 2 x 8 KiB : permuted image [ch][quad][8]

  const int tid = threadIdx.x;
  const int bid = blockIdx.x;
  const int s   = bid & 7;
  const int qg  = (bid >> 3) & 15;
  const int b   = bid >> 7;
  const int m0  = qg << 8;
  const int w   = tid >> 6, lane = tid & 63, quad = lane >> 4, l16 = lane & 15;
  const int rbase = m0 + w * 64;

  // Q B-fragments [k=ch][n=qrow]: 4 row-tiles x 2 k-steps (Q pre-scaled)
  short8 qa[4][2];
#pragma unroll
  for (int mt = 0; mt < 4; ++mt)
#pragma unroll
    for (int kk = 0; kk < 2; ++kk)
      qa[mt][kk] = *(const short8*)&qb[((size_t)b * N_ + rbase + mt * 16 + l16) * 64 + kk * 32 + quad * 8];

  float lsum[4] = {0.f, 0.f, 0.f, 0.f};
  f32x4 accO[8][4];                  // O^T [ch-tile][qrow-tile]
#pragma unroll
  for (int vt = 0; vt < 8; ++vt)
#pragma unroll
    for (int mt = 0; mt < 4; ++mt) accO[vt][mt] = (f32x4){0.f, 0.f, 0.f, 0.f};

  auto dma_tile = [&](int kt, int d) {
    const int T = s * NTS + kt;
    const short* kbp = kb + (((size_t)b * N_ + T * 32) << 6);
    {                                // K: 256 x 16B chunks, XOR-swizzled
      const int p = w * 64 + lane;
      const int key = p >> 3, jm = (p & 7) ^ (key & 7);
      __builtin_amdgcn_global_load_lds((gp_t)(kbp + (key << 6) + jm * 8),
                                       (lp_t)&kbuf[d][w * 512], 16, 0, 0);
    }
    const short* vtp = vb + ((size_t)b * 128 + T) * 4096;
#pragma unroll
    for (int t = 0; t < 2; ++t) {    // V: 512 x 16B chunks, LINEAR image copy
      const int p = (w * 2 + t) * 64 + lane;
      __builtin_amdgcn_global_load_lds((gp_t)(vtp + p * 8),
                                       (lp_t)&vbuf[d][(w * 2 + t) * 512], 16, 0, 0);
    }
  };

  dma_tile(0, 0);

  for (int kt = 0; kt < NTS; ++kt) {
    __syncthreads();                 // drains this tile's DMA on all waves
    if (kt + 1 < NTS) dma_tile(kt + 1, (kt + 1) & 1);
    const int d = kt & 1;

    // ---- S^T = K Q^T : 2 key-subtiles x 4 row-tiles ----
    u32x2 ppk[2][4];                 // [ct][mt] packed P (keys ct*16+quad*4+r)
#pragma unroll
    for (int ct = 0; ct < 2; ++ct) {
      const short8 kf0 = *(const short8*)&kbuf[d][((ct * 16 + l16) << 6) + ((quad ^ (l16 & 7)) << 3)];
      const short8 kf1 = *(const short8*)&kbuf[d][((ct * 16 + l16) << 6) + (((4 + quad) ^ (l16 & 7)) << 3)];
#pragma unroll
      for (int mt = 0; mt < 4; ++mt) {
        f32x4 st = (f32x4){0.f, 0.f, 0.f, 0.f};
        st = __builtin_amdgcn_mfma_f32_16x16x32_bf16(kf0, qa[mt][0], st, 0, 0, 0);
        st = __builtin_amdgcn_mfma_f32_16x16x32_bf16(kf1, qa[mt][1], st, 0, 0, 0);
        const float p0 = fexp2(st[0]);
        const float p1 = fexp2(st[1]);
        const float p2 = fexp2(st[2]);
        const float p3 = fexp2(st[3]);
        lsum[mt] += (p0 + p1) + (p2 + p3);
        u32x2 pp;
        pp[0] = pk2(p0, p1);
        pp[1] = pk2(p2, p3);
        ppk[ct][mt] = pp;
      }
    }
    // concat ct0|ct1 -> valid K=32 B-frag under the V key-permutation
    short8 pcat[4];
#pragma unroll
    for (int mt = 0; mt < 4; ++mt) {
      u32x4 u = (u32x4){ppk[0][mt][0], ppk[0][mt][1], ppk[1][mt][0], ppk[1][mt][1]};
      pcat[mt] = __builtin_bit_cast(short8, u);
    }

    // ---- O^T += V^T P^T : K=32, A-frag = single b128, shared across 4 mt ----
#pragma unroll
    for (int vt = 0; vt < 8; ++vt) {
      const short8 vf = *(const short8*)&vbuf[d][((vt * 16 + l16) << 5) + (quad << 3)];
#pragma unroll
      for (int mt = 0; mt < 4; ++mt)
        accO[vt][mt] = __builtin_amdgcn_mfma_f32_16x16x32_bf16(vf, pcat[mt], accO[vt][mt], 0, 0, 0);
    }
  }

  // ---- epilogue: reduce l across quads; store O^T + l ----
#pragma unroll
  for (int mt = 0; mt < 4; ++mt) {
    lsum[mt] += __shfl_xor(lsum[mt], 16);
    lsum[mt] += __shfl_xor(lsum[mt], 32);
  }
  if (quad == 0) {
#pragma unroll
    for (int mt = 0; mt < 4; ++mt)
      lbuf[((size_t)b * SPLITS + s) * N_ + rbase + mt * 16 + l16] = lsum[mt];
  }
#pragma unroll
  for (int vt = 0; vt < 8; ++vt) {
#pragma unroll
    for (int mt = 0; mt < 4; ++mt) {
#pragma unroll
      for (int r = 0; r < 4; ++r) {
        const int ch = vt * 16 + quad * 4 + r;
        Opart[(((size_t)b * SPLITS + s) * C_ + ch) * N_ + rbase + mt * 16 + l16] =
            f2bf(accO[vt][mt][r]);
      }
    }
  }
}

// ---------------------------------------------------------------------------
// Kernel 3: combine splits + residual, linv computed in-block.
// grid = B * (N/64) = 256 blocks; block = 64 n x 128 c.
// ---------------------------------------------------------------------------
__global__ __launch_bounds__(256) void combine_kernel(
    const float* __restrict__ x, const float* __restrict__ gamma,
    const short* __restrict__ Opart, const float* __restrict__ lbuf,
    float* __restrict__ out)
{
  __shared__ float linvL[64];
  const int tid = threadIdx.x;
  const int b   = blockIdx.x >> 6;
  const int n0  = (blockIdx.x & 63) << 6;

  if (tid < 64) {
    float L = 0.f;
#pragma unroll
    for (int s = 0; s < SPLITS; ++s) L += lbuf[((size_t)b * SPLITS + s) * N_ + n0 + tid];
    linvL[tid] = 1.f / L;
  }
  __syncthreads();

  const float g = gamma[0];
  const int n4 = (tid & 15) * 4, cb = tid >> 4;    // cb 0..15
#pragma unroll
  for (int cp = 0; cp < 8; ++cp) {
    const int c = cp * 16 + cb;
    float acc[4] = {0.f, 0.f, 0.f, 0.f};
#pragma unroll
    for (int s = 0; s < SPLITS; ++s) {
      const bf16x4 o4 = *(const bf16x4*)&Opart[(((size_t)b * SPLITS + s) * C_ + c) * N_ + n0 + n4];
#pragma unroll
      for (int j = 0; j < 4; ++j) acc[j] += bf2f(o4[j]);
    }
    const size_t xi = ((size_t)b * C_ + c) * N_ + n0 + n4;
    const float4 xv = *(const float4*)&x[xi];
    float4 ov;
    ov.x = xv.x + g * acc[0] * linvL[n4 + 0];
    ov.y = xv.y + g * acc[1] * linvL[n4 + 1];
    ov.z = xv.z + g * acc[2] * linvL[n4 + 2];
    ov.w = xv.w + g * acc[3] * linvL[n4 + 3];
    *(float4*)&out[xi] = ov;
  }
}

// ---------------------------------------------------------------------------
extern "C" void kernel_launch(void* const* d_in, const int* in_sizes, int n_in,
                              void* d_out, int out_size, void* d_ws, size_t ws_size,
                              hipStream_t stream) {
  const float* x     = (const float*)d_in[0];
  const float* Wq    = (const float*)d_in[1];
  const float* bq    = (const float*)d_in[2];
  const float* Wk    = (const float*)d_in[3];
  const float* bk    = (const float*)d_in[4];
  const float* Wv    = (const float*)d_in[5];
  const float* bv    = (const float*)d_in[6];
  const float* gamma = (const float*)d_in[7];
  float* out = (float*)d_out;

  short* qb = (short*)d_ws;                          // [4][4096][64]  bf16 = 2 MB
  short* kb = qb + (size_t)B_ * N_ * INNER_;         // [4][4096][64]  bf16 = 2 MB
  short* vb = kb + (size_t)B_ * N_ * INNER_;         // permuted V images = 4 MB
  short* Opart = vb + (size_t)B_ * C_ * N_;          // [4][8][128][4096] bf16 = 32 MB
  float* lbuf  = (float*)(Opart + (size_t)B_ * SPLITS * C_ * N_); // [4][8][4096] f32
  float* bp    = lbuf + (size_t)B_ * SPLITS * N_;    // [256] f32
  short* wp    = (short*)(bp + 256);                 // [256][128] bf16

  pack_kernel<<<128, 256, 0, stream>>>(Wq, bq, Wk, bk, Wv, bv, wp, bp);
  qkv_kernel<<<B_ * (N_ / 32), 256, 0, stream>>>(x, wp, bp, qb, kb, vb);
  attn_kernel<<<B_ * 16 * SPLITS, 256, 0, stream>>>(qb, kb, vb, Opart, lbuf);
  combine_kernel<<<B_ * (N_ / 64), 256, 0, stream>>>(x, gamma, Opart, lbuf, out);
}

// Round 12
// 123.392 us; speedup vs baseline: 1.0421x; 1.0069x over previous
//
#include <hip/hip_runtime.h>
#include <cstdint>

#define B_ 4
#define C_ 128
#define INNER_ 64
#define N_ 4096
#define SPLITS 8                  // key-dimension splits
#define KT 32                     // key-tile size
#define NTS 16                    // tiles per split = (N/SPLITS)/KT

typedef __attribute__((ext_vector_type(8))) short short8;
typedef __attribute__((ext_vector_type(4))) short bf16x4;
typedef __attribute__((ext_vector_type(4))) float f32x4;
typedef __attribute__((ext_vector_type(2))) unsigned u32x2;
typedef __attribute__((ext_vector_type(4))) unsigned u32x4;

typedef const __attribute__((address_space(1))) void* gp_t;
typedef __attribute__((address_space(3))) void* lp_t;

// raw barrier with FINE-GRAINED vmcnt: does NOT drain the whole DMA queue
// (unlike __syncthreads, which emits s_waitcnt vmcnt(0) before s_barrier).
#define WAITBAR3() asm volatile("s_waitcnt vmcnt(3)\n\ts_barrier" ::: "memory")
#define WAITBAR0() asm volatile("s_waitcnt vmcnt(0)\n\ts_barrier" ::: "memory")

__device__ __forceinline__ short f2bf(float f) {
  unsigned u = __builtin_bit_cast(unsigned, f);
  unsigned r = (u + 0x7FFFu + ((u >> 16) & 1u)) >> 16;
  return (short)r;
}
__device__ __forceinline__ float bf2f(short s) {
  return __builtin_bit_cast(float, ((unsigned)(unsigned short)s) << 16);
}
__device__ __forceinline__ float fexp2(float x) {
#if __has_builtin(__builtin_amdgcn_exp2f)
  return __builtin_amdgcn_exp2f(x);
#else
  return exp2f(x);
#endif
}
__device__ __forceinline__ unsigned pk2(float lo, float hi) {
#if __has_builtin(__builtin_amdgcn_cvt_pk_bf16_f32)
  typedef __attribute__((ext_vector_type(2))) __bf16 bfp;
  bfp v = __builtin_amdgcn_cvt_pk_bf16_f32(lo, hi);
  return __builtin_bit_cast(unsigned, v);
#else
  return (unsigned)(unsigned short)f2bf(lo) | ((unsigned)(unsigned short)f2bf(hi) << 16);
#endif
}

// ---------------------------------------------------------------------------
// Kernel 0: pack Wq|Wk|Wv -> bf16 [256][128], biases -> f32 [256].
// ---------------------------------------------------------------------------
__global__ __launch_bounds__(256) void pack_kernel(
    const float* __restrict__ Wq, const float* __restrict__ bq,
    const float* __restrict__ Wk, const float* __restrict__ bk,
    const float* __restrict__ Wv, const float* __restrict__ bv,
    short* __restrict__ wp, float* __restrict__ bp)
{
  const int idx = blockIdx.x * 256 + threadIdx.x;   // 32768
  const int o = idx >> 7, c = idx & 127;
  float v;
  if (o < 64)       v = Wq[o * C_ + c];
  else if (o < 128) v = Wk[(o - 64) * C_ + c];
  else              v = Wv[(o - 128) * C_ + c];
  wp[idx] = f2bf(v);
  if (c == 0)
    bp[o] = (o < 64) ? bq[o] : (o < 128) ? bk[o - 64] : bv[o - 128];
}

// ---------------------------------------------------------------------------
// Kernel 1: QKV 1x1-conv, LDS-staged coalesced outputs (unchanged from R11).
// Q PRE-SCALED by 0.125*log2(e). qb/kb: [B][N][64] bf16.
// vb: per-32-key-tile PERMUTED images:
//   vimg[b][T][ch][quad][e], e=0..7 holds key_local = (e>>2)*16 + quad*4 + (e&3)
// grid = B*(N/32) = 512 blocks (each block emits exactly one V tile).
// ---------------------------------------------------------------------------
__global__ __launch_bounds__(256) void qkv_kernel(
    const float* __restrict__ x, const short* __restrict__ wp,
    const float* __restrict__ bp,
    short* __restrict__ qg, short* __restrict__ kg, short* __restrict__ vg)
{
  __shared__ short xT[32 * 136];   // [n][c] bf16, pad 128->136
  __shared__ short outb[256 * 40]; // [o][n] bf16, pad 32->40
  __shared__ float biasL[256];

  const int tid = threadIdx.x;
  const int b   = blockIdx.x >> 7;
  const int n0  = (blockIdx.x & 127) << 5;
  const float QSC = 0.125f * 1.44269504088896340736f;

  biasL[tid] = bp[tid];
  const float* xb = x + (size_t)b * C_ * N_ + n0;
  for (int i = tid; i < 1024; i += 256) {          // 128 c x 8 float4
    const int c = i >> 3, seg = i & 7;
    const float4 v = *(const float4*)&xb[(size_t)c * N_ + seg * 4];
    xT[(seg * 4 + 0) * 136 + c] = f2bf(v.x);
    xT[(seg * 4 + 1) * 136 + c] = f2bf(v.y);
    xT[(seg * 4 + 2) * 136 + c] = f2bf(v.z);
    xT[(seg * 4 + 3) * 136 + c] = f2bf(v.w);
  }
  __syncthreads();

  const int w = tid >> 6, lane = tid & 63, quad = lane >> 4, l16 = lane & 15;

  short8 xf[2][4];
#pragma unroll
  for (int nt = 0; nt < 2; ++nt)
#pragma unroll
    for (int kk = 0; kk < 4; ++kk)
      xf[nt][kk] = *(const short8*)&xT[(nt * 16 + l16) * 136 + kk * 32 + quad * 8];

  if (w < 2) {
    const int obase = w * 64;                      // w0: q (scaled), w1: k
    const float osc = (w == 0) ? QSC : 1.0f;
#pragma unroll
    for (int ot = 0; ot < 4; ++ot) {
      const int o = obase + ot * 16 + l16;
      short8 wf[4];
#pragma unroll
      for (int kk = 0; kk < 4; ++kk)
        wf[kk] = *(const short8*)&wp[(size_t)o * 128 + kk * 32 + quad * 8];
      const float bias = biasL[o];
#pragma unroll
      for (int nt = 0; nt < 2; ++nt) {
        f32x4 acc = (f32x4){0.f, 0.f, 0.f, 0.f};
#pragma unroll
        for (int kk = 0; kk < 4; ++kk)
          acc = __builtin_amdgcn_mfma_f32_16x16x32_bf16(xf[nt][kk], wf[kk], acc, 0, 0, 0);
#pragma unroll
        for (int r = 0; r < 4; ++r)
          outb[o * 40 + nt * 16 + quad * 4 + r] = f2bf((acc[r] + bias) * osc);
      }
    }
  } else {
    const int ob2 = (w - 2) * 64;
#pragma unroll
    for (int ot = 0; ot < 4; ++ot) {
      const int orow = 128 + ob2 + ot * 16 + l16;
      short8 wf[4];
#pragma unroll
      for (int kk = 0; kk < 4; ++kk)
        wf[kk] = *(const short8*)&wp[(size_t)orow * 128 + kk * 32 + quad * 8];
#pragma unroll
      for (int nt = 0; nt < 2; ++nt) {
        f32x4 acc = (f32x4){0.f, 0.f, 0.f, 0.f};
#pragma unroll
        for (int kk = 0; kk < 4; ++kk)
          acc = __builtin_amdgcn_mfma_f32_16x16x32_bf16(wf[kk], xf[nt][kk], acc, 0, 0, 0);
#pragma unroll
        for (int r = 0; r < 4; ++r) {
          const int o_r = 128 + ob2 + ot * 16 + quad * 4 + r;
          outb[o_r * 40 + nt * 16 + l16] = f2bf(acc[r] + biasL[o_r]);
        }
      }
    }
  }
  __syncthreads();

  // q/k coalesced stores: [n][64] rows
  {
    const int n = tid >> 3, oc = tid & 7;
    short8 qv, kv;
#pragma unroll
    for (int j = 0; j < 8; ++j) {
      qv[j] = outb[(oc * 8 + j) * 40 + n];
      kv[j] = outb[(64 + oc * 8 + j) * 40 + n];
    }
    *(short8*)&qg[(((size_t)b * N_ + n0 + n) << 6) + oc * 8] = qv;
    *(short8*)&kg[(((size_t)b * N_ + n0 + n) << 6) + oc * 8] = kv;
  }
  // v permuted tile-image store: this block IS tile T = n0/32 (8 KB contiguous)
  {
    const int T = n0 >> 5;
#pragma unroll
    for (int rep = 0; rep < 2; ++rep) {
      const int idx2 = rep * 256 + tid;            // 0..511
      const int ch = idx2 >> 2, q = idx2 & 3;
      const bf16x4 lo = *(const bf16x4*)&outb[(128 + ch) * 40 + q * 4];
      const bf16x4 hi = *(const bf16x4*)&outb[(128 + ch) * 40 + 16 + q * 4];
      short8 vv;
#pragma unroll
      for (int j = 0; j < 4; ++j) { vv[j] = lo[j]; vv[4 + j] = hi[j]; }
      const size_t tb = ((size_t)b * 128 + T) * 4096 + (size_t)idx2 * 8;
      *(short8*)&vg[tb] = vv;
    }
  }
}

// ---------------------------------------------------------------------------
// Kernel 2: split-K flash attention, RAW-BARRIER PIPELINE:
// 3-deep LDS ring (36 KiB), DMA depth 2, s_waitcnt vmcnt(3) + s_barrier
// per iteration (never vmcnt(0) until the last tile) -- the hipBLASLt-style
// fine-grained drain the __syncthreads structure cannot express.
// Wave = 64 q-rows; block = 4 waves; grid = B*16*SPLITS = 512 -> 2 blocks/CU.
// S^T trick + permuted-V K=32 PV. Emits Opart [b][s][c][n] bf16 + lbuf f32.
// ---------------------------------------------------------------------------
__global__ __launch_bounds__(256, 2) void attn_kernel(
    const short* __restrict__ qb, const short* __restrict__ kb,
    const short* __restrict__ vb,
    short* __restrict__ Opart, float* __restrict__ lbuf)
{
  __shared__ short kbuf[3][2048];    // 3 x 4 KiB : [key][64ch], 16B-XOR swizzled
  __shared__ short vbuf[3][4096];    // 3 x 8 KiB : permuted image [ch][quad][8]

  const int tid = threadIdx.x;
  const int bid = blockIdx.x;
  const int s   = bid & 7;
  const int qg  = (bid >> 3) & 15;
  const int b   = bid >> 7;
  const int m0  = qg << 8;
  const int w   = tid >> 6, lane = tid & 63, quad = lane >> 4, l16 = lane & 15;
  const int rbase = m0 + w * 64;

  // Q B-fragments [k=ch][n=qrow]: 4 row-tiles x 2 k-steps (Q pre-scaled)
  short8 qa[4][2];
#pragma unroll
  for (int mt = 0; mt < 4; ++mt)
#pragma unroll
    for (int kk = 0; kk < 2; ++kk)
      qa[mt][kk] = *(const short8*)&qb[((size_t)b * N_ + rbase + mt * 16 + l16) * 64 + kk * 32 + quad * 8];

  float lsum[4] = {0.f, 0.f, 0.f, 0.f};
  f32x4 accO[8][4];                  // O^T [ch-tile][qrow-tile]
#pragma unroll
  for (int vt = 0; vt < 8; ++vt)
#pragma unroll
    for (int mt = 0; mt < 4; ++mt) accO[vt][mt] = (f32x4){0.f, 0.f, 0.f, 0.f};

  // 3 async DMA instrs per wave per tile (vmcnt quantum = 3)
  auto dma_tile = [&](int kt, int d) {
    const int T = s * NTS + kt;
    const short* kbp = kb + (((size_t)b * N_ + T * 32) << 6);
    {                                // K: 256 x 16B chunks, XOR-swizzled
      const int p = w * 64 + lane;
      const int key = p >> 3, jm = (p & 7) ^ (key & 7);
      __builtin_amdgcn_global_load_lds((gp_t)(kbp + (key << 6) + jm * 8),
                                       (lp_t)&kbuf[d][w * 512], 16, 0, 0);
    }
    const short* vtp = vb + ((size_t)b * 128 + T) * 4096;
#pragma unroll
    for (int t = 0; t < 2; ++t) {    // V: 512 x 16B chunks, LINEAR image copy
      const int p = (w * 2 + t) * 64 + lane;
      __builtin_amdgcn_global_load_lds((gp_t)(vtp + p * 8),
                                       (lp_t)&vbuf[d][(w * 2 + t) * 512], 16, 0, 0);
    }
  };

  dma_tile(0, 0);
  dma_tile(1, 1);

#pragma unroll
  for (int kt = 0; kt < NTS; ++kt) {
    // wait for tile kt's 3 DMAs only; tile kt+1's stay in flight
    if (kt + 1 < NTS) { WAITBAR3(); } else { WAITBAR0(); }
    if (kt + 2 < NTS) dma_tile(kt + 2, (kt + 2) % 3);
    const int d = kt % 3;

    // ---- S^T = K Q^T : 2 key-subtiles x 4 row-tiles ----
    u32x2 ppk[2][4];                 // [ct][mt] packed P (keys ct*16+quad*4+r)
#pragma unroll
    for (int ct = 0; ct < 2; ++ct) {
      const short8 kf0 = *(const short8*)&kbuf[d][((ct * 16 + l16) << 6) + ((quad ^ (l16 & 7)) << 3)];
      const short8 kf1 = *(const short8*)&kbuf[d][((ct * 16 + l16) << 6) + (((4 + quad) ^ (l16 & 7)) << 3)];
#pragma unroll
      for (int mt = 0; mt < 4; ++mt) {
        f32x4 st = (f32x4){0.f, 0.f, 0.f, 0.f};
        st = __builtin_amdgcn_mfma_f32_16x16x32_bf16(kf0, qa[mt][0], st, 0, 0, 0);
        st = __builtin_amdgcn_mfma_f32_16x16x32_bf16(kf1, qa[mt][1], st, 0, 0, 0);
        const float p0 = fexp2(st[0]);
        const float p1 = fexp2(st[1]);
        const float p2 = fexp2(st[2]);
        const float p3 = fexp2(st[3]);
        lsum[mt] += (p0 + p1) + (p2 + p3);
        u32x2 pp;
        pp[0] = pk2(p0, p1);
        pp[1] = pk2(p2, p3);
        ppk[ct][mt] = pp;
      }
    }
    // concat ct0|ct1 -> valid K=32 B-frag under the V key-permutation
    short8 pcat[4];
#pragma unroll
    for (int mt = 0; mt < 4; ++mt) {
      u32x4 u = (u32x4){ppk[0][mt][0], ppk[0][mt][1], ppk[1][mt][0], ppk[1][mt][1]};
      pcat[mt] = __builtin_bit_cast(short8, u);
    }

    // ---- O^T += V^T P^T : K=32, A-frag = single b128, shared across 4 mt ----
#pragma unroll
    for (int vt = 0; vt < 8; ++vt) {
      const short8 vf = *(const short8*)&vbuf[d][((vt * 16 + l16) << 5) + (quad << 3)];
#pragma unroll
      for (int mt = 0; mt < 4; ++mt)
        accO[vt][mt] = __builtin_amdgcn_mfma_f32_16x16x32_bf16(vf, pcat[mt], accO[vt][mt], 0, 0, 0);
    }
  }

  // ---- epilogue: reduce l across quads; store O^T + l ----
#pragma unroll
  for (int mt = 0; mt < 4; ++mt) {
    lsum[mt] += __shfl_xor(lsum[mt], 16);
    lsum[mt] += __shfl_xor(lsum[mt], 32);
  }
  if (quad == 0) {
#pragma unroll
    for (int mt = 0; mt < 4; ++mt)
      lbuf[((size_t)b * SPLITS + s) * N_ + rbase + mt * 16 + l16] = lsum[mt];
  }
#pragma unroll
  for (int vt = 0; vt < 8; ++vt) {
#pragma unroll
    for (int mt = 0; mt < 4; ++mt) {
#pragma unroll
      for (int r = 0; r < 4; ++r) {
        const int ch = vt * 16 + quad * 4 + r;
        Opart[(((size_t)b * SPLITS + s) * C_ + ch) * N_ + rbase + mt * 16 + l16] =
            f2bf(accO[vt][mt][r]);
      }
    }
  }
}

// ---------------------------------------------------------------------------
// Kernel 3: combine splits + residual, linv computed in-block.
// grid = B * (N/64) = 256 blocks; block = 64 n x 128 c.
// ---------------------------------------------------------------------------
__global__ __launch_bounds__(256) void combine_kernel(
    const float* __restrict__ x, const float* __restrict__ gamma,
    const short* __restrict__ Opart, const float* __restrict__ lbuf,
    float* __restrict__ out)
{
  __shared__ float linvL[64];
  const int tid = threadIdx.x;
  const int b   = blockIdx.x >> 6;
  const int n0  = (blockIdx.x & 63) << 6;

  if (tid < 64) {
    float L = 0.f;
#pragma unroll
    for (int s = 0; s < SPLITS; ++s) L += lbuf[((size_t)b * SPLITS + s) * N_ + n0 + tid];
    linvL[tid] = 1.f / L;
  }
  __syncthreads();

  const float g = gamma[0];
  const int n4 = (tid & 15) * 4, cb = tid >> 4;    // cb 0..15
#pragma unroll
  for (int cp = 0; cp < 8; ++cp) {
    const int c = cp * 16 + cb;
    float acc[4] = {0.f, 0.f, 0.f, 0.f};
#pragma unroll
    for (int s = 0; s < SPLITS; ++s) {
      const bf16x4 o4 = *(const bf16x4*)&Opart[(((size_t)b * SPLITS + s) * C_ + c) * N_ + n0 + n4];
#pragma unroll
      for (int j = 0; j < 4; ++j) acc[j] += bf2f(o4[j]);
    }
    const size_t xi = ((size_t)b * C_ + c) * N_ + n0 + n4;
    const float4 xv = *(const float4*)&x[xi];
    float4 ov;
    ov.x = xv.x + g * acc[0] * linvL[n4 + 0];
    ov.y = xv.y + g * acc[1] * linvL[n4 + 1];
    ov.z = xv.z + g * acc[2] * linvL[n4 + 2];
    ov.w = xv.w + g * acc[3] * linvL[n4 + 3];
    *(float4*)&out[xi] = ov;
  }
}

// ---------------------------------------------------------------------------
extern "C" void kernel_launch(void* const* d_in, const int* in_sizes, int n_in,
                              void* d_out, int out_size, void* d_ws, size_t ws_size,
                              hipStream_t stream) {
  const float* x     = (const float*)d_in[0];
  const float* Wq    = (const float*)d_in[1];
  const float* bq    = (const float*)d_in[2];
  const float* Wk    = (const float*)d_in[3];
  const float* bk    = (const float*)d_in[4];
  const float* Wv    = (const float*)d_in[5];
  const float* bv    = (const float*)d_in[6];
  const float* gamma = (const float*)d_in[7];
  float* out = (float*)d_out;

  short* qb = (short*)d_ws;                          // [4][4096][64]  bf16 = 2 MB
  short* kb = qb + (size_t)B_ * N_ * INNER_;         // [4][4096][64]  bf16 = 2 MB
  short* vb = kb + (size_t)B_ * N_ * INNER_;         // permuted V images = 4 MB
  short* Opart = vb + (size_t)B_ * C_ * N_;          // [4][8][128][4096] bf16 = 32 MB
  float* lbuf  = (float*)(Opart + (size_t)B_ * SPLITS * C_ * N_); // [4][8][4096] f32
  float* bp    = lbuf + (size_t)B_ * SPLITS * N_;    // [256] f32
  short* wp    = (short*)(bp + 256);                 // [256][128] bf16

  pack_kernel<<<128, 256, 0, stream>>>(Wq, bq, Wk, bk, Wv, bv, wp, bp);
  qkv_kernel<<<B_ * (N_ / 32), 256, 0, stream>>>(x, wp, bp, qb, kb, vb);
  attn_kernel<<<B_ * 16 * SPLITS, 256, 0, stream>>>(qb, kb, vb, Opart, lbuf);
  combine_kernel<<<B_ * (N_ / 64), 256, 0, stream>>>(x, gamma, Opart, lbuf, out);
}

// Round 13
// 122.605 us; speedup vs baseline: 1.0488x; 1.0064x over previous
//
#include <hip/hip_runtime.h>
#include <cstdint>

#define B_ 4
#define C_ 128
#define INNER_ 64
#define N_ 4096
#define SPLITS 8                  // key-dimension splits
#define KT 64                     // key-tile size (2 x 32-key subtiles)
#define NTS 8                     // tiles per split = (N/SPLITS)/KT

typedef __attribute__((ext_vector_type(8))) short short8;
typedef __attribute__((ext_vector_type(4))) short bf16x4;
typedef __attribute__((ext_vector_type(4))) float f32x4;
typedef __attribute__((ext_vector_type(2))) unsigned u32x2;
typedef __attribute__((ext_vector_type(4))) unsigned u32x4;

typedef const __attribute__((address_space(1))) void* gp_t;
typedef __attribute__((address_space(3))) void* lp_t;

// raw barrier with FINE-GRAINED vmcnt (no full DMA-queue drain).
// steady state: 2 tiles x 6 DMA instrs in flight; wait for the older 6.
#define WAITBAR6() asm volatile("s_waitcnt vmcnt(6)\n\ts_barrier" ::: "memory")
#define WAITBAR0() asm volatile("s_waitcnt vmcnt(0)\n\ts_barrier" ::: "memory")

__device__ __forceinline__ short f2bf(float f) {
  unsigned u = __builtin_bit_cast(unsigned, f);
  unsigned r = (u + 0x7FFFu + ((u >> 16) & 1u)) >> 16;
  return (short)r;
}
__device__ __forceinline__ float bf2f(short s) {
  return __builtin_bit_cast(float, ((unsigned)(unsigned short)s) << 16);
}
__device__ __forceinline__ float fexp2(float x) {
#if __has_builtin(__builtin_amdgcn_exp2f)
  return __builtin_amdgcn_exp2f(x);
#else
  return exp2f(x);
#endif
}
__device__ __forceinline__ unsigned pk2(float lo, float hi) {
#if __has_builtin(__builtin_amdgcn_cvt_pk_bf16_f32)
  typedef __attribute__((ext_vector_type(2))) __bf16 bfp;
  bfp v = __builtin_amdgcn_cvt_pk_bf16_f32(lo, hi);
  return __builtin_bit_cast(unsigned, v);
#else
  return (unsigned)(unsigned short)f2bf(lo) | ((unsigned)(unsigned short)f2bf(hi) << 16);
#endif
}

// ---------------------------------------------------------------------------
// Kernel 0: pack Wq|Wk|Wv -> bf16 [256][128], biases -> f32 [256].
// ---------------------------------------------------------------------------
__global__ __launch_bounds__(256) void pack_kernel(
    const float* __restrict__ Wq, const float* __restrict__ bq,
    const float* __restrict__ Wk, const float* __restrict__ bk,
    const float* __restrict__ Wv, const float* __restrict__ bv,
    short* __restrict__ wp, float* __restrict__ bp)
{
  const int idx = blockIdx.x * 256 + threadIdx.x;   // 32768
  const int o = idx >> 7, c = idx & 127;
  float v;
  if (o < 64)       v = Wq[o * C_ + c];
  else if (o < 128) v = Wk[(o - 64) * C_ + c];
  else              v = Wv[(o - 128) * C_ + c];
  wp[idx] = f2bf(v);
  if (c == 0)
    bp[o] = (o < 64) ? bq[o] : (o < 128) ? bk[o - 64] : bv[o - 128];
}

// ---------------------------------------------------------------------------
// Kernel 1: QKV 1x1-conv, LDS-staged coalesced outputs (unchanged from R12).
// Q PRE-SCALED by 0.125*log2(e). qb/kb: [B][N][64] bf16.
// vb: per-32-key-tile PERMUTED images:
//   vimg[b][T][ch][quad][e], e=0..7 holds key_local = (e>>2)*16 + quad*4 + (e&3)
// grid = B*(N/32) = 512 blocks (each block emits exactly one V tile).
// ---------------------------------------------------------------------------
__global__ __launch_bounds__(256) void qkv_kernel(
    const float* __restrict__ x, const short* __restrict__ wp,
    const float* __restrict__ bp,
    short* __restrict__ qg, short* __restrict__ kg, short* __restrict__ vg)
{
  __shared__ short xT[32 * 136];   // [n][c] bf16, pad 128->136
  __shared__ short outb[256 * 40]; // [o][n] bf16, pad 32->40
  __shared__ float biasL[256];

  const int tid = threadIdx.x;
  const int b   = blockIdx.x >> 7;
  const int n0  = (blockIdx.x & 127) << 5;
  const float QSC = 0.125f * 1.44269504088896340736f;

  biasL[tid] = bp[tid];
  const float* xb = x + (size_t)b * C_ * N_ + n0;
  for (int i = tid; i < 1024; i += 256) {          // 128 c x 8 float4
    const int c = i >> 3, seg = i & 7;
    const float4 v = *(const float4*)&xb[(size_t)c * N_ + seg * 4];
    xT[(seg * 4 + 0) * 136 + c] = f2bf(v.x);
    xT[(seg * 4 + 1) * 136 + c] = f2bf(v.y);
    xT[(seg * 4 + 2) * 136 + c] = f2bf(v.z);
    xT[(seg * 4 + 3) * 136 + c] = f2bf(v.w);
  }
  __syncthreads();

  const int w = tid >> 6, lane = tid & 63, quad = lane >> 4, l16 = lane & 15;

  short8 xf[2][4];
#pragma unroll
  for (int nt = 0; nt < 2; ++nt)
#pragma unroll
    for (int kk = 0; kk < 4; ++kk)
      xf[nt][kk] = *(const short8*)&xT[(nt * 16 + l16) * 136 + kk * 32 + quad * 8];

  if (w < 2) {
    const int obase = w * 64;                      // w0: q (scaled), w1: k
    const float osc = (w == 0) ? QSC : 1.0f;
#pragma unroll
    for (int ot = 0; ot < 4; ++ot) {
      const int o = obase + ot * 16 + l16;
      short8 wf[4];
#pragma unroll
      for (int kk = 0; kk < 4; ++kk)
        wf[kk] = *(const short8*)&wp[(size_t)o * 128 + kk * 32 + quad * 8];
      const float bias = biasL[o];
#pragma unroll
      for (int nt = 0; nt < 2; ++nt) {
        f32x4 acc = (f32x4){0.f, 0.f, 0.f, 0.f};
#pragma unroll
        for (int kk = 0; kk < 4; ++kk)
          acc = __builtin_amdgcn_mfma_f32_16x16x32_bf16(xf[nt][kk], wf[kk], acc, 0, 0, 0);
#pragma unroll
        for (int r = 0; r < 4; ++r)
          outb[o * 40 + nt * 16 + quad * 4 + r] = f2bf((acc[r] + bias) * osc);
      }
    }
  } else {
    const int ob2 = (w - 2) * 64;
#pragma unroll
    for (int ot = 0; ot < 4; ++ot) {
      const int orow = 128 + ob2 + ot * 16 + l16;
      short8 wf[4];
#pragma unroll
      for (int kk = 0; kk < 4; ++kk)
        wf[kk] = *(const short8*)&wp[(size_t)orow * 128 + kk * 32 + quad * 8];
#pragma unroll
      for (int nt = 0; nt < 2; ++nt) {
        f32x4 acc = (f32x4){0.f, 0.f, 0.f, 0.f};
#pragma unroll
        for (int kk = 0; kk < 4; ++kk)
          acc = __builtin_amdgcn_mfma_f32_16x16x32_bf16(wf[kk], xf[nt][kk], acc, 0, 0, 0);
#pragma unroll
        for (int r = 0; r < 4; ++r) {
          const int o_r = 128 + ob2 + ot * 16 + quad * 4 + r;
          outb[o_r * 40 + nt * 16 + l16] = f2bf(acc[r] + biasL[o_r]);
        }
      }
    }
  }
  __syncthreads();

  // q/k coalesced stores: [n][64] rows
  {
    const int n = tid >> 3, oc = tid & 7;
    short8 qv, kv;
#pragma unroll
    for (int j = 0; j < 8; ++j) {
      qv[j] = outb[(oc * 8 + j) * 40 + n];
      kv[j] = outb[(64 + oc * 8 + j) * 40 + n];
    }
    *(short8*)&qg[(((size_t)b * N_ + n0 + n) << 6) + oc * 8] = qv;
    *(short8*)&kg[(((size_t)b * N_ + n0 + n) << 6) + oc * 8] = kv;
  }
  // v permuted tile-image store: this block IS tile T = n0/32 (8 KB contiguous)
  {
    const int T = n0 >> 5;
#pragma unroll
    for (int rep = 0; rep < 2; ++rep) {
      const int idx2 = rep * 256 + tid;            // 0..511
      const int ch = idx2 >> 2, q = idx2 & 3;
      const bf16x4 lo = *(const bf16x4*)&outb[(128 + ch) * 40 + q * 4];
      const bf16x4 hi = *(const bf16x4*)&outb[(128 + ch) * 40 + 16 + q * 4];
      short8 vv;
#pragma unroll
      for (int j = 0; j < 4; ++j) { vv[j] = lo[j]; vv[4 + j] = hi[j]; }
      const size_t tb = ((size_t)b * 128 + T) * 4096 + (size_t)idx2 * 8;
      *(short8*)&vg[tb] = vv;
    }
  }
}

// ---------------------------------------------------------------------------
// Kernel 2: split-K flash attention, KT=64 + 64-row waves + vmcnt ring:
// 8 barriers per block (half of R12), 3-deep 24 KiB-tile LDS ring (72 KiB),
// DMA depth 2, steady-state s_waitcnt vmcnt(6) + s_barrier.
// Each 64-key tile = two 32-key subtiles via the proven S^T + permuted-V
// K=32 PV path. grid = B*16*SPLITS = 512 -> 2 blocks/CU fully resident.
// Emits Opart [b][s][c][n] bf16 + lbuf f32.
// ---------------------------------------------------------------------------
__global__ __launch_bounds__(256, 2) void attn_kernel(
    const short* __restrict__ qb, const short* __restrict__ kb,
    const short* __restrict__ vb,
    short* __restrict__ Opart, float* __restrict__ lbuf)
{
  __shared__ short kbuf[3][4096];    // 3 x 8 KiB : [key][64ch], 16B-XOR swizzled
  __shared__ short vbuf[3][8192];    // 3 x 16 KiB: 2 permuted 32-key images

  const int tid = threadIdx.x;
  const int bid = blockIdx.x;
  const int s   = bid & 7;
  const int qg  = (bid >> 3) & 15;
  const int b   = bid >> 7;
  const int m0  = qg << 8;
  const int w   = tid >> 6, lane = tid & 63, quad = lane >> 4, l16 = lane & 15;
  const int rbase = m0 + w * 64;

  // Q B-fragments [k=ch][n=qrow]: 4 row-tiles x 2 k-steps (Q pre-scaled)
  short8 qa[4][2];
#pragma unroll
  for (int mt = 0; mt < 4; ++mt)
#pragma unroll
    for (int kk = 0; kk < 2; ++kk)
      qa[mt][kk] = *(const short8*)&qb[((size_t)b * N_ + rbase + mt * 16 + l16) * 64 + kk * 32 + quad * 8];

  float lsum[4] = {0.f, 0.f, 0.f, 0.f};
  f32x4 accO[8][4];                  // O^T [ch-tile][qrow-tile]
#pragma unroll
  for (int vt = 0; vt < 8; ++vt)
#pragma unroll
    for (int mt = 0; mt < 4; ++mt) accO[vt][mt] = (f32x4){0.f, 0.f, 0.f, 0.f};

  // 6 async DMA instrs per wave per 64-key tile (vmcnt quantum = 6)
  auto dma_tile = [&](int kt, int d) {
    const int T = s * NTS + kt;      // 64-key tile index
    const short* kbp = kb + (((size_t)b * N_ + T * 64) << 6);
#pragma unroll
    for (int t = 0; t < 2; ++t) {    // K: 512 x 16B chunks, XOR-swizzled
      const int p = (w * 2 + t) * 64 + lane;
      const int key = p >> 3, jm = (p & 7) ^ (key & 7);
      __builtin_amdgcn_global_load_lds((gp_t)(kbp + (key << 6) + jm * 8),
                                       (lp_t)&kbuf[d][(w * 2 + t) * 512], 16, 0, 0);
    }
    // V: two consecutive 32-key permuted images = 8 KB contiguous
    const short* vtp = vb + ((size_t)b * 128 + T * 2) * 4096;
#pragma unroll
    for (int t = 0; t < 4; ++t) {
      const int p = (w * 4 + t) * 64 + lane;
      __builtin_amdgcn_global_load_lds((gp_t)(vtp + p * 8),
                                       (lp_t)&vbuf[d][(w * 4 + t) * 512], 16, 0, 0);
    }
  };

  dma_tile(0, 0);
  dma_tile(1, 1);

#pragma unroll
  for (int kt = 0; kt < NTS; ++kt) {
    // wait for tile kt's 6 DMAs only; tile kt+1's 6 stay in flight
    if (kt + 1 < NTS) { WAITBAR6(); } else { WAITBAR0(); }
    if (kt + 2 < NTS) dma_tile(kt + 2, (kt + 2) % 3);
    const int d = kt % 3;

#pragma unroll
    for (int h = 0; h < 2; ++h) {    // two 32-key subtiles
      const short* kh = &kbuf[d][h * 2048];
      const short* vh = &vbuf[d][h * 4096];

      // ---- S^T = K Q^T : 2 key-subtiles x 4 row-tiles ----
      u32x2 ppk[2][4];
#pragma unroll
      for (int ct = 0; ct < 2; ++ct) {
        const short8 kf0 = *(const short8*)&kh[((ct * 16 + l16) << 6) + ((quad ^ (l16 & 7)) << 3)];
        const short8 kf1 = *(const short8*)&kh[((ct * 16 + l16) << 6) + (((4 + quad) ^ (l16 & 7)) << 3)];
#pragma unroll
        for (int mt = 0; mt < 4; ++mt) {
          f32x4 st = (f32x4){0.f, 0.f, 0.f, 0.f};
          st = __builtin_amdgcn_mfma_f32_16x16x32_bf16(kf0, qa[mt][0], st, 0, 0, 0);
          st = __builtin_amdgcn_mfma_f32_16x16x32_bf16(kf1, qa[mt][1], st, 0, 0, 0);
          const float p0 = fexp2(st[0]);
          const float p1 = fexp2(st[1]);
          const float p2 = fexp2(st[2]);
          const float p3 = fexp2(st[3]);
          lsum[mt] += (p0 + p1) + (p2 + p3);
          u32x2 pp;
          pp[0] = pk2(p0, p1);
          pp[1] = pk2(p2, p3);
          ppk[ct][mt] = pp;
        }
      }
      short8 pcat[4];
#pragma unroll
      for (int mt = 0; mt < 4; ++mt) {
        u32x4 u = (u32x4){ppk[0][mt][0], ppk[0][mt][1], ppk[1][mt][0], ppk[1][mt][1]};
        pcat[mt] = __builtin_bit_cast(short8, u);
      }

      // ---- O^T += V^T P^T : K=32, A-frag = single b128, shared 4 mt ----
#pragma unroll
      for (int vt = 0; vt < 8; ++vt) {
        const short8 vf = *(const short8*)&vh[((vt * 16 + l16) << 5) + (quad << 3)];
#pragma unroll
        for (int mt = 0; mt < 4; ++mt)
          accO[vt][mt] = __builtin_amdgcn_mfma_f32_16x16x32_bf16(vf, pcat[mt], accO[vt][mt], 0, 0, 0);
      }
    }
  }

  // ---- epilogue: reduce l across quads; store O^T + l ----
#pragma unroll
  for (int mt = 0; mt < 4; ++mt) {
    lsum[mt] += __shfl_xor(lsum[mt], 16);
    lsum[mt] += __shfl_xor(lsum[mt], 32);
  }
  if (quad == 0) {
#pragma unroll
    for (int mt = 0; mt < 4; ++mt)
      lbuf[((size_t)b * SPLITS + s) * N_ + rbase + mt * 16 + l16] = lsum[mt];
  }
#pragma unroll
  for (int vt = 0; vt < 8; ++vt) {
#pragma unroll
    for (int mt = 0; mt < 4; ++mt) {
#pragma unroll
      for (int r = 0; r < 4; ++r) {
        const int ch = vt * 16 + quad * 4 + r;
        Opart[(((size_t)b * SPLITS + s) * C_ + ch) * N_ + rbase + mt * 16 + l16] =
            f2bf(accO[vt][mt][r]);
      }
    }
  }
}

// ---------------------------------------------------------------------------
// Kernel 3: combine splits + residual, linv computed in-block.
// grid = B * (N/64) = 256 blocks; block = 64 n x 128 c.
// ---------------------------------------------------------------------------
__global__ __launch_bounds__(256) void combine_kernel(
    const float* __restrict__ x, const float* __restrict__ gamma,
    const short* __restrict__ Opart, const float* __restrict__ lbuf,
    float* __restrict__ out)
{
  __shared__ float linvL[64];
  const int tid = threadIdx.x;
  const int b   = blockIdx.x >> 6;
  const int n0  = (blockIdx.x & 63) << 6;

  if (tid < 64) {
    float L = 0.f;
#pragma unroll
    for (int s = 0; s < SPLITS; ++s) L += lbuf[((size_t)b * SPLITS + s) * N_ + n0 + tid];
    linvL[tid] = 1.f / L;
  }
  __syncthreads();

  const float g = gamma[0];
  const int n4 = (tid & 15) * 4, cb = tid >> 4;    // cb 0..15
#pragma unroll
  for (int cp = 0; cp < 8; ++cp) {
    const int c = cp * 16 + cb;
    float acc[4] = {0.f, 0.f, 0.f, 0.f};
#pragma unroll
    for (int s = 0; s < SPLITS; ++s) {
      const bf16x4 o4 = *(const bf16x4*)&Opart[(((size_t)b * SPLITS + s) * C_ + c) * N_ + n0 + n4];
#pragma unroll
      for (int j = 0; j < 4; ++j) acc[j] += bf2f(o4[j]);
    }
    const size_t xi = ((size_t)b * C_ + c) * N_ + n0 + n4;
    const float4 xv = *(const float4*)&x[xi];
    float4 ov;
    ov.x = xv.x + g * acc[0] * linvL[n4 + 0];
    ov.y = xv.y + g * acc[1] * linvL[n4 + 1];
    ov.z = xv.z + g * acc[2] * linvL[n4 + 2];
    ov.w = xv.w + g * acc[3] * linvL[n4 + 3];
    *(float4*)&out[xi] = ov;
  }
}

// ---------------------------------------------------------------------------
extern "C" void kernel_launch(void* const* d_in, const int* in_sizes, int n_in,
                              void* d_out, int out_size, void* d_ws, size_t ws_size,
                              hipStream_t stream) {
  const float* x     = (const float*)d_in[0];
  const float* Wq    = (const float*)d_in[1];
  const float* bq    = (const float*)d_in[2];
  const float* Wk    = (const float*)d_in[3];
  const float* bk    = (const float*)d_in[4];
  const float* Wv    = (const float*)d_in[5];
  const float* bv    = (const float*)d_in[6];
  const float* gamma = (const float*)d_in[7];
  float* out = (float*)d_out;

  short* qb = (short*)d_ws;                          // [4][4096][64]  bf16 = 2 MB
  short* kb = qb + (size_t)B_ * N_ * INNER_;         // [4][4096][64]  bf16 = 2 MB
  short* vb = kb + (size_t)B_ * N_ * INNER_;         // permuted V images = 4 MB
  short* Opart = vb + (size_t)B_ * C_ * N_;          // [4][8][128][4096] bf16 = 32 MB
  float* lbuf  = (float*)(Opart + (size_t)B_ * SPLITS * C_ * N_); // [4][8][4096] f32
  float* bp    = lbuf + (size_t)B_ * SPLITS * N_;    // [256] f32
  short* wp    = (short*)(bp + 256);                 // [256][128] bf16

  pack_kernel<<<128, 256, 0, stream>>>(Wq, bq, Wk, bk, Wv, bv, wp, bp);
  qkv_kernel<<<B_ * (N_ / 32), 256, 0, stream>>>(x, wp, bp, qb, kb, vb);
  attn_kernel<<<B_ * 16 * SPLITS, 256, 0, stream>>>(qb, kb, vb, Opart, lbuf);
  combine_kernel<<<B_ * (N_ / 64), 256, 0, stream>>>(x, gamma, Opart, lbuf, out);
}